// Round 10
// baseline (463.117 us; speedup 1.0000x reference)
//
#include <hip/hip_runtime.h>
#include <hip/hip_bf16.h>
#include <math.h>

// Structural constants (from reference code): D=64, H=4, dh=16.
constexpr int D  = 64;
constexpr int H  = 4;
constexpr int DH = D / H;  // 16

// ---------------------------------------------------------------------------
// Hypothesis ledger (rounds 1-9):
//   inputs fp32                  PROVEN (r1 NaN via bf16-read / r2 finite)
//   OUTPUT COMPARED AS FP32      NEW — the test's "(bf16" label is a hardcoded
//     f-string literal, not the dtype.  Evidence: r6 probe wrote bf16 bits
//     into u16[0] with u16[1]=0 -> fp32 denormal ~0 -> error exactly 5.656250
//     (all-zero signature).  Also explains rounds 2-9: bf16 halves packed
//     pairwise into fp32 words = ref-scale decorrelated error regardless of
//     pipeline correctness.  ALL FOUR edge decodes are un-falsified; reverting
//     to the reference-literal decode: [2,E], rows=half0 (segment+Q),
//     cols=half1 (K,V).
//   N=1e5, E=8e5, dict order     PROVEN (r4 bit-identical to r2)
//   edge data int32, valid ids   PROVEN (r5 == r7 bit-identical)
// ---------------------------------------------------------------------------

// ---------------------------------------------------------------------------
// Kernel 1: per-node QKV projection (gather commutes with the matmul:
// project 100K nodes once instead of 800K edges).  Block = 4 nodes x 64 cols;
// emb row staged in LDS; all fp32.
// ---------------------------------------------------------------------------
__global__ __launch_bounds__(256) void qkv_kernel(
    const float* __restrict__ emb,
    const float* __restrict__ Wq,
    const float* __restrict__ Wk,
    const float* __restrict__ Wv,
    int N,
    float* __restrict__ Q, float* __restrict__ K, float* __restrict__ V) {
    __shared__ float srow[4][D];
    const int tid  = threadIdx.x;
    const int sub  = tid >> 6;
    const int col  = tid & 63;
    const int node = blockIdx.x * 4 + sub;

    if (node < N) {
        srow[sub][col] = emb[(size_t)node * D + col];
    }
    __syncthreads();
    if (node >= N) return;

    float aq = 0.f, ak = 0.f, av = 0.f;
#pragma unroll 8
    for (int j = 0; j < D; ++j) {
        const float x = srow[sub][j];
        aq = fmaf(x, Wq[j * D + col], aq);
        ak = fmaf(x, Wk[j * D + col], ak);
        av = fmaf(x, Wv[j * D + col], av);
    }
    const size_t o = (size_t)node * D + col;
    Q[o] = aq;
    K[o] = ak;
    V[o] = av;
}

// ---------------------------------------------------------------------------
// Kernel 2: per-(edge, head) attention score.
//   att = clip(dot(Q[rows[e],h,:], K[cols[e],h,:]), -10, 10); ex = exp(att)
//   expatt[e,h] = ex;  norm[rows[e],h] += ex  (atomic)
// ---------------------------------------------------------------------------
__global__ __launch_bounds__(256) void score_kernel(
    const int* __restrict__ rows, const int* __restrict__ cols,
    const float* __restrict__ Q, const float* __restrict__ K,
    float* __restrict__ expatt, float* __restrict__ norm, int E) {
    const int t = blockIdx.x * blockDim.x + threadIdx.x;
    if (t >= E * H) return;
    const int e = t >> 2;
    const int h = t & 3;
    const int r = rows[e];
    const int c = cols[e];

    const float4* qp = (const float4*)(Q + (size_t)r * D + h * DH);
    const float4* kp = (const float4*)(K + (size_t)c * D + h * DH);
    float acc = 0.f;
#pragma unroll
    for (int i = 0; i < 4; ++i) {
        const float4 q = qp[i];
        const float4 k = kp[i];
        acc += q.x * k.x + q.y * k.y + q.z * k.z + q.w * k.w;
    }
    acc = fminf(fmaxf(acc, -10.f), 10.f);
    const float ex = __expf(acc);
    expatt[t] = ex;
    atomicAdd(&norm[(size_t)r * H + h], ex);
}

// ---------------------------------------------------------------------------
// Kernel 3: per-(edge, dim) weighted-value scatter-add, directly into the
// fp32 output buffer (zeroed by stream-ordered memset beforehand).
//   out[rows[e],d] += (expatt[e,h]/(norm[rows[e],h]+1e-8)) * V[cols[e],d]
// ---------------------------------------------------------------------------
__global__ __launch_bounds__(256) void agg_kernel(
    const int* __restrict__ rows, const int* __restrict__ cols,
    const float* __restrict__ V, const float* __restrict__ expatt,
    const float* __restrict__ norm, float* __restrict__ out, int E) {
    const int t = blockIdx.x * blockDim.x + threadIdx.x;
    const int e = t >> 6;
    const int d = t & 63;
    if (e >= E) return;
    const int r = rows[e];
    const int c = cols[e];
    const int h = d >> 4;

    const float ex  = expatt[(size_t)e * H + h];
    const float nm  = norm[(size_t)r * H + h] + 1e-8f;
    const float att = ex / nm;
    const float val = att * V[(size_t)c * D + d];
    atomicAdd(&out[(size_t)r * D + d], val);
}

extern "C" void kernel_launch(void* const* d_in, const int* in_sizes, int n_in,
                              void* d_out, int out_size, void* d_ws, size_t ws_size,
                              hipStream_t stream) {
    const float* emb = (const float*)d_in[0];
    const float* Wq  = (const float*)d_in[1];
    const float* Wk  = (const float*)d_in[2];
    const float* Wv  = (const float*)d_in[3];
    const int*   w32 = (const int*)d_in[4];

    const int N = in_sizes[0] / D;   // 100000 (validated r4)
    const int E = in_sizes[4] / 2;   // 800000 (validated r4)
    const size_t ND = (size_t)N * D;

    // Reference-literal decode: [2,E] halves, rows = edge_index[0].
    const int* rows = w32;
    const int* cols = w32 + E;

    // Workspace (fp32), 91.2 MB: Q | K | V | norm | expatt.
    float* ws     = (float*)d_ws;
    float* Q      = ws;
    float* K      = ws + ND;
    float* V      = ws + 2 * ND;
    float* norm   = ws + 3 * ND;
    float* expatt = ws + 3 * ND + (size_t)N * H;

    float* out = (float*)d_out;      // fp32 output (ledger: fp32-compared)

    // Zero norm and the output accumulator (both poisoned 0xAA by harness).
    hipMemsetAsync(norm, 0, (size_t)N * H * sizeof(float), stream);
    hipMemsetAsync(out, 0, (size_t)out_size * sizeof(float), stream);

    // 1) QKV projection
    qkv_kernel<<<(N + 3) / 4, 256, 0, stream>>>(emb, Wq, Wk, Wv, N, Q, K, V);

    // 2) Scores + softmax denominators
    score_kernel<<<((size_t)E * H + 255) / 256, 256, 0, stream>>>(
        rows, cols, Q, K, expatt, norm, E);

    // 3) Weighted-value scatter straight into fp32 output
    agg_kernel<<<((size_t)E * D + 255) / 256, 256, 0, stream>>>(
        rows, cols, V, expatt, norm, out, E);
}

// Round 11
// 461.323 us; speedup vs baseline: 1.0039x; 1.0039x over previous
//
#include <hip/hip_runtime.h>
#include <hip/hip_bf16.h>
#include <math.h>

// Structural constants (from reference code): D=64, H=4, dh=16.
constexpr int D  = 64;
constexpr int H  = 4;
constexpr int DH = D / H;  // 16

// ---------------------------------------------------------------------------
// R10 baseline: PASS, 463 us, absmax 0.0078.  agg=178us (atomic/latency-bound:
// VALUBusy 27%, HBM 25%), score ~110us, qkv ~80us.
// R11 change: score+agg FUSED via post-normalization —
//   sum_e (ex/(norm+eps))*V  ==  (sum_e ex*V)/(norm+eps)   (norm is segment-
// constant), so one edge pass accumulates out_unnorm and norm together; a
// cheap per-node kernel divides afterwards.  Deletes the score pass's Q/K
// gather traffic + the 12.8MB expatt round-trip; atomic count unchanged.
// ---------------------------------------------------------------------------

// ---------------------------------------------------------------------------
// Kernel 1: per-node QKV projection (gather commutes with the matmul:
// project 100K nodes once instead of 800K edges).  Block = 4 nodes x 64 cols;
// emb row staged in LDS; all fp32.
// ---------------------------------------------------------------------------
__global__ __launch_bounds__(256) void qkv_kernel(
    const float* __restrict__ emb,
    const float* __restrict__ Wq,
    const float* __restrict__ Wk,
    const float* __restrict__ Wv,
    int N,
    float* __restrict__ Q, float* __restrict__ K, float* __restrict__ V) {
    __shared__ float srow[4][D];
    const int tid  = threadIdx.x;
    const int sub  = tid >> 6;
    const int col  = tid & 63;
    const int node = blockIdx.x * 4 + sub;

    if (node < N) {
        srow[sub][col] = emb[(size_t)node * D + col];
    }
    __syncthreads();
    if (node >= N) return;

    float aq = 0.f, ak = 0.f, av = 0.f;
#pragma unroll 8
    for (int j = 0; j < D; ++j) {
        const float x = srow[sub][j];
        aq = fmaf(x, Wq[j * D + col], aq);
        ak = fmaf(x, Wk[j * D + col], ak);
        av = fmaf(x, Wv[j * D + col], av);
    }
    const size_t o = (size_t)node * D + col;
    Q[o] = aq;
    K[o] = ak;
    V[o] = av;
}

// ---------------------------------------------------------------------------
// Kernel 2 (FUSED edge pass): one wave per edge, lane = dim d (0..63).
//   p_d = Q[r,d]*K[c,d]; per-head dot via shfl_xor reduction within the
//   16-lane head group; ex = exp(clip(dot));
//   norm[r,h]  += ex          (1 atomic per (edge,head), lane d%16==0)
//   outU[r,d]  += ex * V[c,d] (unnormalized; 64 atomics per edge)
// ---------------------------------------------------------------------------
__global__ __launch_bounds__(256) void edge_kernel(
    const int* __restrict__ rows, const int* __restrict__ cols,
    const float* __restrict__ Q, const float* __restrict__ K,
    const float* __restrict__ V,
    float* __restrict__ norm, float* __restrict__ outU, int E) {
    const int t = blockIdx.x * blockDim.x + threadIdx.x;
    const int e = t >> 6;
    const int d = t & 63;
    if (e >= E) return;
    const int r = rows[e];          // wave-uniform (e = wave id)
    const int c = cols[e];

    const float qd = Q[(size_t)r * D + d];
    const float kd = K[(size_t)c * D + d];
    float p = qd * kd;
    // Reduce within the 16-lane head group (masks <16 never cross groups).
    p += __shfl_xor(p, 1);
    p += __shfl_xor(p, 2);
    p += __shfl_xor(p, 4);
    p += __shfl_xor(p, 8);
    const float att = fminf(fmaxf(p, -10.f), 10.f);
    const float ex  = __expf(att);

    if ((d & 15) == 0) {
        atomicAdd(&norm[(size_t)r * H + (d >> 4)], ex);
    }
    const float val = ex * V[(size_t)c * D + d];
    atomicAdd(&outU[(size_t)r * D + d], val);
}

// ---------------------------------------------------------------------------
// Kernel 3: post-normalization.  out[n,d] = outU[n,d] / (norm[n,h] + 1e-8)
// ---------------------------------------------------------------------------
__global__ __launch_bounds__(256) void norm_kernel(
    const float* __restrict__ norm, float* __restrict__ out, int n) {
    const int t = blockIdx.x * blockDim.x + threadIdx.x;
    if (t >= n) return;
    const int node = t >> 6;
    const int h    = (t & 63) >> 4;
    out[t] = out[t] / (norm[(size_t)node * H + h] + 1e-8f);
}

extern "C" void kernel_launch(void* const* d_in, const int* in_sizes, int n_in,
                              void* d_out, int out_size, void* d_ws, size_t ws_size,
                              hipStream_t stream) {
    const float* emb = (const float*)d_in[0];
    const float* Wq  = (const float*)d_in[1];
    const float* Wk  = (const float*)d_in[2];
    const float* Wv  = (const float*)d_in[3];
    const int*   w32 = (const int*)d_in[4];

    const int N = in_sizes[0] / D;   // 100000
    const int E = in_sizes[4] / 2;   // 800000
    const size_t ND = (size_t)N * D;

    // Reference decode (validated r10): [2,E] halves, rows = edge_index[0].
    const int* rows = w32;
    const int* cols = w32 + E;

    // Workspace (fp32), 78.4 MB: Q | K | V | norm.
    float* ws   = (float*)d_ws;
    float* Q    = ws;
    float* K    = ws + ND;
    float* V    = ws + 2 * ND;
    float* norm = ws + 3 * ND;

    float* out = (float*)d_out;      // fp32 output, used as the accumulator

    // Zero norm and the output accumulator (poisoned 0xAA by harness).
    hipMemsetAsync(norm, 0, (size_t)N * H * sizeof(float), stream);
    hipMemsetAsync(out, 0, (size_t)out_size * sizeof(float), stream);

    // 1) QKV projection
    qkv_kernel<<<(N + 3) / 4, 256, 0, stream>>>(emb, Wq, Wk, Wv, N, Q, K, V);

    // 2) Fused edge pass: unnormalized scatter + softmax denominators
    edge_kernel<<<((size_t)E * D + 255) / 256, 256, 0, stream>>>(
        rows, cols, Q, K, V, norm, out, E);

    // 3) Post-normalize per (node, head)
    norm_kernel<<<((int)ND + 255) / 256, 256, 0, stream>>>(norm, out, (int)ND);
}

// Round 12
// 371.648 us; speedup vs baseline: 1.2461x; 1.2413x over previous
//
#include <hip/hip_runtime.h>
#include <hip/hip_bf16.h>
#include <math.h>

// Structural constants (from reference code): D=64, H=4, dh=16.
constexpr int D  = 64;
constexpr int H  = 4;

// ---------------------------------------------------------------------------
// R10: 463us (3-pass, atomics).  R11: 461us — fusion neutral: edge pass is
// bound by per-edge transactions (random gathers + 65 atomics/edge), WRITE
// amplification 9x (225MB for 25.6MB output).
// R12: counting-sort edges by destination (histogram + 2-level scan + scatter)
// then ONE WAVE PER NODE aggregates its edge group entirely in registers:
// zero atomics, Q coalesced, single plain store per output element.
// ---------------------------------------------------------------------------

// Kernel 1: per-node QKV projection (unchanged from r10/r11).
__global__ __launch_bounds__(256) void qkv_kernel(
    const float* __restrict__ emb,
    const float* __restrict__ Wq,
    const float* __restrict__ Wk,
    const float* __restrict__ Wv,
    int N,
    float* __restrict__ Q, float* __restrict__ K, float* __restrict__ V) {
    __shared__ float srow[4][D];
    const int tid  = threadIdx.x;
    const int sub  = tid >> 6;
    const int col  = tid & 63;
    const int node = blockIdx.x * 4 + sub;

    if (node < N) srow[sub][col] = emb[(size_t)node * D + col];
    __syncthreads();
    if (node >= N) return;

    float aq = 0.f, ak = 0.f, av = 0.f;
#pragma unroll 8
    for (int j = 0; j < D; ++j) {
        const float x = srow[sub][j];
        aq = fmaf(x, Wq[j * D + col], aq);
        ak = fmaf(x, Wk[j * D + col], ak);
        av = fmaf(x, Wv[j * D + col], av);
    }
    const size_t o = (size_t)node * D + col;
    Q[o] = aq;
    K[o] = ak;
    V[o] = av;
}

// --- Counting sort: histogram -> block sums -> scan -> block scan -> scatter

__global__ __launch_bounds__(256) void histo_kernel(
    const int* __restrict__ rows, int* __restrict__ cnt, int E) {
    const int e = blockIdx.x * 256 + threadIdx.x;
    if (e < E) atomicAdd(&cnt[rows[e]], 1);
}

// Per-256-chunk sums of cnt.
__global__ __launch_bounds__(256) void block_sum_kernel(
    const int* __restrict__ cnt, int* __restrict__ bsum, int N) {
    __shared__ int s[256];
    const int tid = threadIdx.x;
    const int i   = blockIdx.x * 256 + tid;
    s[tid] = (i < N) ? cnt[i] : 0;
    __syncthreads();
    for (int st = 128; st > 0; st >>= 1) {
        if (tid < st) s[tid] += s[tid + st];
        __syncthreads();
    }
    if (tid == 0) bsum[blockIdx.x] = s[0];
}

// Exclusive scan of bsum (NB <= 1024) in a single block.
__global__ __launch_bounds__(1024) void scan_bsum_kernel(
    const int* __restrict__ bsum, int* __restrict__ bsumsc, int NB) {
    __shared__ int s[1024];
    const int tid = threadIdx.x;
    const int x   = (tid < NB) ? bsum[tid] : 0;
    s[tid] = x;
    __syncthreads();
    for (int offs = 1; offs < 1024; offs <<= 1) {
        int v = 0;
        if (tid >= offs) v = s[tid - offs];
        __syncthreads();
        if (tid >= offs) s[tid] += v;
        __syncthreads();
    }
    if (tid < NB) bsumsc[tid] = s[tid] - x;   // exclusive
}

// Per-chunk exclusive scan + global base -> off[] and cur[].
__global__ __launch_bounds__(256) void block_scan_kernel(
    const int* __restrict__ cnt, const int* __restrict__ bsumsc,
    int* __restrict__ off, int* __restrict__ cur, int N, int E) {
    __shared__ int s[256];
    const int tid = threadIdx.x;
    const int i   = blockIdx.x * 256 + tid;
    const int x   = (i < N) ? cnt[i] : 0;
    s[tid] = x;
    __syncthreads();
    for (int offs = 1; offs < 256; offs <<= 1) {
        int v = 0;
        if (tid >= offs) v = s[tid - offs];
        __syncthreads();
        if (tid >= offs) s[tid] += v;
        __syncthreads();
    }
    if (i < N) {
        const int val = bsumsc[blockIdx.x] + s[tid] - x;   // exclusive
        off[i] = val;
        cur[i] = val;
    }
    if (i == 0) off[N] = E;
}

// Scatter source ids into destination-grouped order.
__global__ __launch_bounds__(256) void scatter_kernel(
    const int* __restrict__ rows, const int* __restrict__ cols,
    int* __restrict__ cur, int* __restrict__ sc, int E) {
    const int e = blockIdx.x * 256 + threadIdx.x;
    if (e >= E) return;
    const int p = atomicAdd(&cur[rows[e]], 1);
    sc[p] = cols[e];
}

// ---------------------------------------------------------------------------
// Kernel 2: atomic-free aggregation.  One wave per destination node, lane=d.
//   q = Q[n,d] (coalesced); loop over grouped sources c:
//   dot via 4x shfl_xor within 16-lane head group; accV += ex*V[c,d];
//   accN += ex;  out[n,d] = accV/(accN+1e-8).  2-wide unroll for load ILP.
// ---------------------------------------------------------------------------
__global__ __launch_bounds__(256) void aggregate_kernel(
    const int* __restrict__ off, const int* __restrict__ sc,
    const float* __restrict__ Q, const float* __restrict__ K,
    const float* __restrict__ V, float* __restrict__ out, int N) {
    const int t = blockIdx.x * 256 + threadIdx.x;
    const int n = t >> 6;
    const int d = t & 63;
    if (n >= N) return;

    const int off0 = off[n];
    const int off1 = off[n + 1];
    const float q  = Q[(size_t)n * D + d];

    float accV = 0.f, accN = 0.f;
    int i = off0;
    for (; i + 1 < off1; i += 2) {
        const int c0 = sc[i];
        const int c1 = sc[i + 1];
        const float k0 = K[(size_t)c0 * D + d];
        const float k1 = K[(size_t)c1 * D + d];
        const float v0 = V[(size_t)c0 * D + d];
        const float v1 = V[(size_t)c1 * D + d];
        float p0 = q * k0;
        float p1 = q * k1;
        p0 += __shfl_xor(p0, 1);  p1 += __shfl_xor(p1, 1);
        p0 += __shfl_xor(p0, 2);  p1 += __shfl_xor(p1, 2);
        p0 += __shfl_xor(p0, 4);  p1 += __shfl_xor(p1, 4);
        p0 += __shfl_xor(p0, 8);  p1 += __shfl_xor(p1, 8);
        const float e0 = __expf(fminf(fmaxf(p0, -10.f), 10.f));
        const float e1 = __expf(fminf(fmaxf(p1, -10.f), 10.f));
        accN += e0 + e1;
        accV = fmaf(e0, v0, accV);
        accV = fmaf(e1, v1, accV);
    }
    if (i < off1) {
        const int c0 = sc[i];
        const float k0 = K[(size_t)c0 * D + d];
        const float v0 = V[(size_t)c0 * D + d];
        float p0 = q * k0;
        p0 += __shfl_xor(p0, 1);
        p0 += __shfl_xor(p0, 2);
        p0 += __shfl_xor(p0, 4);
        p0 += __shfl_xor(p0, 8);
        const float e0 = __expf(fminf(fmaxf(p0, -10.f), 10.f));
        accN += e0;
        accV = fmaf(e0, v0, accV);
    }
    out[(size_t)n * D + d] = accV / (accN + 1e-8f);
}

extern "C" void kernel_launch(void* const* d_in, const int* in_sizes, int n_in,
                              void* d_out, int out_size, void* d_ws, size_t ws_size,
                              hipStream_t stream) {
    const float* emb = (const float*)d_in[0];
    const float* Wq  = (const float*)d_in[1];
    const float* Wk  = (const float*)d_in[2];
    const float* Wv  = (const float*)d_in[3];
    const int*   w32 = (const int*)d_in[4];

    const int N  = in_sizes[0] / D;   // 100000
    const int E  = in_sizes[4] / 2;   // 800000
    const int NB = (N + 255) / 256;   // 391 (must be <= 1024)
    const size_t ND = (size_t)N * D;

    const int* rows = w32;            // validated r10: [2,E], rows = half 0
    const int* cols = w32 + E;

    // Workspace (~81.4 MB): Q | K | V | cnt | off | cur | bsum | bsumsc | sc
    float* ws     = (float*)d_ws;
    float* Q      = ws;
    float* K      = ws + ND;
    float* V      = ws + 2 * ND;
    int*   cnt    = (int*)(ws + 3 * ND);
    int*   off    = cnt + N;          // N+1
    int*   cur    = off + N + 1;
    int*   bsum   = cur + N;
    int*   bsumsc = bsum + NB;
    int*   sc     = bsumsc + NB;

    float* out = (float*)d_out;

    hipMemsetAsync(cnt, 0, (size_t)N * sizeof(int), stream);

    // 1) QKV projection
    qkv_kernel<<<(N + 3) / 4, 256, 0, stream>>>(emb, Wq, Wk, Wv, N, Q, K, V);

    // 2) Counting sort of edges by destination
    histo_kernel<<<(E + 255) / 256, 256, 0, stream>>>(rows, cnt, E);
    block_sum_kernel<<<NB, 256, 0, stream>>>(cnt, bsum, N);
    scan_bsum_kernel<<<1, 1024, 0, stream>>>(bsum, bsumsc, NB);
    block_scan_kernel<<<NB, 256, 0, stream>>>(cnt, bsumsc, off, cur, N, E);
    scatter_kernel<<<(E + 255) / 256, 256, 0, stream>>>(rows, cols, cur, sc, E);

    // 3) Atomic-free aggregation: one wave per node
    aggregate_kernel<<<((size_t)N * 64 + 255) / 256, 256, 0, stream>>>(
        off, sc, Q, K, V, out, N);
}

// Round 13
// 280.199 us; speedup vs baseline: 1.6528x; 1.3264x over previous
//
#include <hip/hip_runtime.h>
#include <hip/hip_bf16.h>
#include <math.h>

// Structural constants (from reference code): D=64, H=4, dh=16.
constexpr int D  = 64;
constexpr int H  = 4;

// ---------------------------------------------------------------------------
// R12: 372us.  Counting-sort + atomic-free aggregate WORKED, but exposed
// qkv_kernel at 164us (VALUBusy 21%, HBM 7% -> issue/latency-bound: 1 output
// per thread, 2 loads per FMA).  R13: register-tiled qkv GEMM — 4 nodes x
// 4 cols x 3 matrices = 48 accumulators/thread; emb tile transposed in LDS
// (stride 65), all 3 W in LDS; inner loop = 4x ds_read_b128 + 48 FMA.
// Everything else unchanged from r12 (proven).
// ---------------------------------------------------------------------------

// ---------------------------------------------------------------------------
// Kernel 1: QKV projection, register-tiled.  Block = 256 threads handles a
// 64-node x 64-col tile for all 3 matrices.  Thread (rn, cn) computes nodes
// 4rn..4rn+3 x cols 4cn..4cn+3.
// ---------------------------------------------------------------------------
__global__ __launch_bounds__(256) void qkv_kernel(
    const float* __restrict__ emb,
    const float* __restrict__ Wq,
    const float* __restrict__ Wk,
    const float* __restrict__ Wv,
    int N,
    float* __restrict__ Q, float* __restrict__ K, float* __restrict__ V) {
    __shared__ float sW[3][64][64];     // 48 KB, all three weight matrices
    __shared__ float sE[64][65];        // emb tile TRANSPOSED [j][node], pad 65

    const int tid = threadIdx.x;
    const int n0  = blockIdx.x * 64;    // first node of this block's tile

    // Stage W (once per block): 3072 float4, 12 per thread.
    const float* wsrc[3] = {Wq, Wk, Wv};
#pragma unroll
    for (int k = 0; k < 12; ++k) {
        const int idx  = tid + k * 256;       // 0..3071
        const int m    = idx >> 10;           // matrix
        const int rest = idx & 1023;          // float4 within matrix
        const float4 w = ((const float4*)wsrc[m])[rest];
        ((float4*)&sW[m][0][0])[rest] = w;
    }
    // Stage emb tile, transposed: 1024 float4 reads, scatter-store into sE.
#pragma unroll
    for (int k = 0; k < 4; ++k) {
        const int idx  = tid + k * 256;       // 0..1023
        const int node = idx >> 4;            // 0..63
        const int jq   = idx & 15;            // float4 within row
        float4 v = make_float4(0.f, 0.f, 0.f, 0.f);
        if (n0 + node < N) v = ((const float4*)emb)[(size_t)(n0 + node) * 16 + jq];
        sE[jq * 4 + 0][node] = v.x;
        sE[jq * 4 + 1][node] = v.y;
        sE[jq * 4 + 2][node] = v.z;
        sE[jq * 4 + 3][node] = v.w;
    }
    __syncthreads();

    const int rn = tid >> 4;            // node group 0..15 (4 nodes each)
    const int cn = tid & 15;            // col group 0..15 (4 cols each)

    float acc[3][4][4];
#pragma unroll
    for (int m = 0; m < 3; ++m)
#pragma unroll
        for (int a = 0; a < 4; ++a)
#pragma unroll
            for (int b = 0; b < 4; ++b) acc[m][a][b] = 0.f;

#pragma unroll 8
    for (int j = 0; j < 64; ++j) {
        const float4 a  = *(const float4*)&sE[j][rn * 4];
        const float4 bq = *(const float4*)&sW[0][j][cn * 4];
        const float4 bk = *(const float4*)&sW[1][j][cn * 4];
        const float4 bv = *(const float4*)&sW[2][j][cn * 4];
        const float an[4] = {a.x, a.y, a.z, a.w};
        const float bqa[4] = {bq.x, bq.y, bq.z, bq.w};
        const float bka[4] = {bk.x, bk.y, bk.z, bk.w};
        const float bva[4] = {bv.x, bv.y, bv.z, bv.w};
#pragma unroll
        for (int x = 0; x < 4; ++x) {
#pragma unroll
            for (int y = 0; y < 4; ++y) {
                acc[0][x][y] = fmaf(an[x], bqa[y], acc[0][x][y]);
                acc[1][x][y] = fmaf(an[x], bka[y], acc[1][x][y]);
                acc[2][x][y] = fmaf(an[x], bva[y], acc[2][x][y]);
            }
        }
    }

    float* dst[3] = {Q, K, V};
#pragma unroll
    for (int x = 0; x < 4; ++x) {
        const int node = n0 + rn * 4 + x;
        if (node >= N) break;
#pragma unroll
        for (int m = 0; m < 3; ++m) {
            float4 o;
            o.x = acc[m][x][0]; o.y = acc[m][x][1];
            o.z = acc[m][x][2]; o.w = acc[m][x][3];
            ((float4*)dst[m])[(size_t)node * 16 + cn] = o;
        }
    }
}

// --- Counting sort: histogram -> block sums -> scan -> block scan -> scatter

__global__ __launch_bounds__(256) void histo_kernel(
    const int* __restrict__ rows, int* __restrict__ cnt, int E) {
    const int e = blockIdx.x * 256 + threadIdx.x;
    if (e < E) atomicAdd(&cnt[rows[e]], 1);
}

__global__ __launch_bounds__(256) void block_sum_kernel(
    const int* __restrict__ cnt, int* __restrict__ bsum, int N) {
    __shared__ int s[256];
    const int tid = threadIdx.x;
    const int i   = blockIdx.x * 256 + tid;
    s[tid] = (i < N) ? cnt[i] : 0;
    __syncthreads();
    for (int st = 128; st > 0; st >>= 1) {
        if (tid < st) s[tid] += s[tid + st];
        __syncthreads();
    }
    if (tid == 0) bsum[blockIdx.x] = s[0];
}

__global__ __launch_bounds__(1024) void scan_bsum_kernel(
    const int* __restrict__ bsum, int* __restrict__ bsumsc, int NB) {
    __shared__ int s[1024];
    const int tid = threadIdx.x;
    const int x   = (tid < NB) ? bsum[tid] : 0;
    s[tid] = x;
    __syncthreads();
    for (int offs = 1; offs < 1024; offs <<= 1) {
        int v = 0;
        if (tid >= offs) v = s[tid - offs];
        __syncthreads();
        if (tid >= offs) s[tid] += v;
        __syncthreads();
    }
    if (tid < NB) bsumsc[tid] = s[tid] - x;   // exclusive
}

__global__ __launch_bounds__(256) void block_scan_kernel(
    const int* __restrict__ cnt, const int* __restrict__ bsumsc,
    int* __restrict__ off, int* __restrict__ cur, int N, int E) {
    __shared__ int s[256];
    const int tid = threadIdx.x;
    const int i   = blockIdx.x * 256 + tid;
    const int x   = (i < N) ? cnt[i] : 0;
    s[tid] = x;
    __syncthreads();
    for (int offs = 1; offs < 256; offs <<= 1) {
        int v = 0;
        if (tid >= offs) v = s[tid - offs];
        __syncthreads();
        if (tid >= offs) s[tid] += v;
        __syncthreads();
    }
    if (i < N) {
        const int val = bsumsc[blockIdx.x] + s[tid] - x;   // exclusive
        off[i] = val;
        cur[i] = val;
    }
    if (i == 0) off[N] = E;
}

__global__ __launch_bounds__(256) void scatter_kernel(
    const int* __restrict__ rows, const int* __restrict__ cols,
    int* __restrict__ cur, int* __restrict__ sc, int E) {
    const int e = blockIdx.x * 256 + threadIdx.x;
    if (e >= E) return;
    const int p = atomicAdd(&cur[rows[e]], 1);
    sc[p] = cols[e];
}

// ---------------------------------------------------------------------------
// Kernel 2: atomic-free aggregation (unchanged from r12).  One wave per
// destination node, lane = dim; registers-only accumulate; one plain store.
// ---------------------------------------------------------------------------
__global__ __launch_bounds__(256) void aggregate_kernel(
    const int* __restrict__ off, const int* __restrict__ sc,
    const float* __restrict__ Q, const float* __restrict__ K,
    const float* __restrict__ V, float* __restrict__ out, int N) {
    const int t = blockIdx.x * 256 + threadIdx.x;
    const int n = t >> 6;
    const int d = t & 63;
    if (n >= N) return;

    const int off0 = off[n];
    const int off1 = off[n + 1];
    const float q  = Q[(size_t)n * D + d];

    float accV = 0.f, accN = 0.f;
    int i = off0;
    for (; i + 1 < off1; i += 2) {
        const int c0 = sc[i];
        const int c1 = sc[i + 1];
        const float k0 = K[(size_t)c0 * D + d];
        const float k1 = K[(size_t)c1 * D + d];
        const float v0 = V[(size_t)c0 * D + d];
        const float v1 = V[(size_t)c1 * D + d];
        float p0 = q * k0;
        float p1 = q * k1;
        p0 += __shfl_xor(p0, 1);  p1 += __shfl_xor(p1, 1);
        p0 += __shfl_xor(p0, 2);  p1 += __shfl_xor(p1, 2);
        p0 += __shfl_xor(p0, 4);  p1 += __shfl_xor(p1, 4);
        p0 += __shfl_xor(p0, 8);  p1 += __shfl_xor(p1, 8);
        const float e0 = __expf(fminf(fmaxf(p0, -10.f), 10.f));
        const float e1 = __expf(fminf(fmaxf(p1, -10.f), 10.f));
        accN += e0 + e1;
        accV = fmaf(e0, v0, accV);
        accV = fmaf(e1, v1, accV);
    }
    if (i < off1) {
        const int c0 = sc[i];
        const float k0 = K[(size_t)c0 * D + d];
        const float v0 = V[(size_t)c0 * D + d];
        float p0 = q * k0;
        p0 += __shfl_xor(p0, 1);
        p0 += __shfl_xor(p0, 2);
        p0 += __shfl_xor(p0, 4);
        p0 += __shfl_xor(p0, 8);
        const float e0 = __expf(fminf(fmaxf(p0, -10.f), 10.f));
        accN += e0;
        accV = fmaf(e0, v0, accV);
    }
    out[(size_t)n * D + d] = accV / (accN + 1e-8f);
}

extern "C" void kernel_launch(void* const* d_in, const int* in_sizes, int n_in,
                              void* d_out, int out_size, void* d_ws, size_t ws_size,
                              hipStream_t stream) {
    const float* emb = (const float*)d_in[0];
    const float* Wq  = (const float*)d_in[1];
    const float* Wk  = (const float*)d_in[2];
    const float* Wv  = (const float*)d_in[3];
    const int*   w32 = (const int*)d_in[4];

    const int N  = in_sizes[0] / D;   // 100000
    const int E  = in_sizes[4] / 2;   // 800000
    const int NB = (N + 255) / 256;   // 391 (<= 1024)
    const size_t ND = (size_t)N * D;

    const int* rows = w32;            // validated r10: [2,E], rows = half 0
    const int* cols = w32 + E;

    // Workspace (~81.4 MB): Q | K | V | cnt | off | cur | bsum | bsumsc | sc
    float* ws     = (float*)d_ws;
    float* Q      = ws;
    float* K      = ws + ND;
    float* V      = ws + 2 * ND;
    int*   cnt    = (int*)(ws + 3 * ND);
    int*   off    = cnt + N;          // N+1
    int*   cur    = off + N + 1;
    int*   bsum   = cur + N;
    int*   bsumsc = bsum + NB;
    int*   sc     = bsumsc + NB;

    float* out = (float*)d_out;

    hipMemsetAsync(cnt, 0, (size_t)N * sizeof(int), stream);

    // 1) QKV projection (register-tiled GEMM)
    qkv_kernel<<<(N + 63) / 64, 256, 0, stream>>>(emb, Wq, Wk, Wv, N, Q, K, V);

    // 2) Counting sort of edges by destination
    histo_kernel<<<(E + 255) / 256, 256, 0, stream>>>(rows, cnt, E);
    block_sum_kernel<<<NB, 256, 0, stream>>>(cnt, bsum, N);
    scan_bsum_kernel<<<1, 1024, 0, stream>>>(bsum, bsumsc, NB);
    block_scan_kernel<<<NB, 256, 0, stream>>>(cnt, bsumsc, off, cur, N, E);
    scatter_kernel<<<(E + 255) / 256, 256, 0, stream>>>(rows, cols, cur, sc, E);

    // 3) Atomic-free aggregation: one wave per node
    aggregate_kernel<<<((size_t)N * 64 + 255) / 256, 256, 0, stream>>>(
        off, sc, Q, K, V, out, N);
}

// Round 15
// 271.857 us; speedup vs baseline: 1.7035x; 1.0307x over previous
//
#include <hip/hip_runtime.h>
#include <math.h>

// Structural constants (from reference code): D=64, H=4, dh=16.
constexpr int D  = 64;
constexpr int H  = 4;

// ---------------------------------------------------------------------------
// R13: 280us.  R14 failed to COMPILE (__hip_bfloat16 has no .data member on
// this ROCm) — same plan, raw-bit bf16 pack/unpack instead.
// Plan: KV packed as bf16 INTERLEAVED per-dim pairs [k_d, v_d] — one 256B row
// per source node serves both operands: 1 gather transaction/edge (was 2),
// half the gather bytes, KV buffer 25.6MB (2x LLC/L2 hit density).
// Q stays fp32.  Fallback if absmax > 0.113: V back to fp32.
// ---------------------------------------------------------------------------

// bf16 helpers (raw bits; no __hip_bfloat16 dependency)
__device__ __forceinline__ unsigned short f32_to_bf16(float f) {
    const unsigned int u = __float_as_uint(f);
    return (unsigned short)((u + 0x7FFFu + ((u >> 16) & 1u)) >> 16);  // RNE
}
__device__ __forceinline__ float bf16_to_f32(unsigned short h) {
    return __uint_as_float(((unsigned int)h) << 16);
}

// ---------------------------------------------------------------------------
// Kernel 1: QKV projection, register-tiled (r13 structure).  Block = 256
// threads handles a 64-node x 64-col tile.  Outputs: Q fp32 row-major,
// KV bf16 interleaved: KV[node*128 + 2d] = K[node,d], [..+1] = V[node,d].
// ---------------------------------------------------------------------------
__global__ __launch_bounds__(256) void qkv_kernel(
    const float* __restrict__ emb,
    const float* __restrict__ Wq,
    const float* __restrict__ Wk,
    const float* __restrict__ Wv,
    int N,
    float* __restrict__ Q, unsigned short* __restrict__ KV) {
    __shared__ float sW[3][64][64];     // 48 KB, all three weight matrices
    __shared__ float sE[64][65];        // emb tile TRANSPOSED [j][node], pad 65

    const int tid = threadIdx.x;
    const int n0  = blockIdx.x * 64;    // first node of this block's tile

    // Stage W (once per block): 3072 float4, 12 per thread.
    const float* wsrc[3] = {Wq, Wk, Wv};
#pragma unroll
    for (int k = 0; k < 12; ++k) {
        const int idx  = tid + k * 256;       // 0..3071
        const int m    = idx >> 10;           // matrix
        const int rest = idx & 1023;          // float4 within matrix
        const float4 w = ((const float4*)wsrc[m])[rest];
        ((float4*)&sW[m][0][0])[rest] = w;
    }
    // Stage emb tile, transposed.
#pragma unroll
    for (int k = 0; k < 4; ++k) {
        const int idx  = tid + k * 256;       // 0..1023
        const int node = idx >> 4;            // 0..63
        const int jq   = idx & 15;            // float4 within row
        float4 v = make_float4(0.f, 0.f, 0.f, 0.f);
        if (n0 + node < N) v = ((const float4*)emb)[(size_t)(n0 + node) * 16 + jq];
        sE[jq * 4 + 0][node] = v.x;
        sE[jq * 4 + 1][node] = v.y;
        sE[jq * 4 + 2][node] = v.z;
        sE[jq * 4 + 3][node] = v.w;
    }
    __syncthreads();

    const int rn = tid >> 4;            // node group 0..15 (4 nodes each)
    const int cn = tid & 15;            // col group 0..15 (4 cols each)

    float acc[3][4][4];
#pragma unroll
    for (int m = 0; m < 3; ++m)
#pragma unroll
        for (int a = 0; a < 4; ++a)
#pragma unroll
            for (int b = 0; b < 4; ++b) acc[m][a][b] = 0.f;

#pragma unroll 8
    for (int j = 0; j < 64; ++j) {
        const float4 a  = *(const float4*)&sE[j][rn * 4];
        const float4 bq = *(const float4*)&sW[0][j][cn * 4];
        const float4 bk = *(const float4*)&sW[1][j][cn * 4];
        const float4 bv = *(const float4*)&sW[2][j][cn * 4];
        const float an[4]  = {a.x, a.y, a.z, a.w};
        const float bqa[4] = {bq.x, bq.y, bq.z, bq.w};
        const float bka[4] = {bk.x, bk.y, bk.z, bk.w};
        const float bva[4] = {bv.x, bv.y, bv.z, bv.w};
#pragma unroll
        for (int x = 0; x < 4; ++x) {
#pragma unroll
            for (int y = 0; y < 4; ++y) {
                acc[0][x][y] = fmaf(an[x], bqa[y], acc[0][x][y]);
                acc[1][x][y] = fmaf(an[x], bka[y], acc[1][x][y]);
                acc[2][x][y] = fmaf(an[x], bva[y], acc[2][x][y]);
            }
        }
    }

#pragma unroll
    for (int x = 0; x < 4; ++x) {
        const int node = n0 + rn * 4 + x;
        if (node >= N) break;
        // Q fp32
        float4 oq;
        oq.x = acc[0][x][0]; oq.y = acc[0][x][1];
        oq.z = acc[0][x][2]; oq.w = acc[0][x][3];
        ((float4*)Q)[(size_t)node * 16 + cn] = oq;
        // KV bf16 interleaved: 4 (k,v) pairs = 8 ushort = 16 B
        unsigned short pk[8];
#pragma unroll
        for (int y = 0; y < 4; ++y) {
            pk[2 * y]     = f32_to_bf16(acc[1][x][y]);
            pk[2 * y + 1] = f32_to_bf16(acc[2][x][y]);
        }
        *(uint4*)&KV[(size_t)node * 128 + cn * 8] = *(const uint4*)pk;
    }
}

// --- Counting sort: histogram -> block sums -> scan -> block scan -> scatter

__global__ __launch_bounds__(256) void histo_kernel(
    const int* __restrict__ rows, int* __restrict__ cnt, int E) {
    const int e = blockIdx.x * 256 + threadIdx.x;
    if (e < E) atomicAdd(&cnt[rows[e]], 1);
}

__global__ __launch_bounds__(256) void block_sum_kernel(
    const int* __restrict__ cnt, int* __restrict__ bsum, int N) {
    __shared__ int s[256];
    const int tid = threadIdx.x;
    const int i   = blockIdx.x * 256 + tid;
    s[tid] = (i < N) ? cnt[i] : 0;
    __syncthreads();
    for (int st = 128; st > 0; st >>= 1) {
        if (tid < st) s[tid] += s[tid + st];
        __syncthreads();
    }
    if (tid == 0) bsum[blockIdx.x] = s[0];
}

__global__ __launch_bounds__(1024) void scan_bsum_kernel(
    const int* __restrict__ bsum, int* __restrict__ bsumsc, int NB) {
    __shared__ int s[1024];
    const int tid = threadIdx.x;
    const int x   = (tid < NB) ? bsum[tid] : 0;
    s[tid] = x;
    __syncthreads();
    for (int offs = 1; offs < 1024; offs <<= 1) {
        int v = 0;
        if (tid >= offs) v = s[tid - offs];
        __syncthreads();
        if (tid >= offs) s[tid] += v;
        __syncthreads();
    }
    if (tid < NB) bsumsc[tid] = s[tid] - x;   // exclusive
}

__global__ __launch_bounds__(256) void block_scan_kernel(
    const int* __restrict__ cnt, const int* __restrict__ bsumsc,
    int* __restrict__ off, int* __restrict__ cur, int N, int E) {
    __shared__ int s[256];
    const int tid = threadIdx.x;
    const int i   = blockIdx.x * 256 + tid;
    const int x   = (i < N) ? cnt[i] : 0;
    s[tid] = x;
    __syncthreads();
    for (int offs = 1; offs < 256; offs <<= 1) {
        int v = 0;
        if (tid >= offs) v = s[tid - offs];
        __syncthreads();
        if (tid >= offs) s[tid] += v;
        __syncthreads();
    }
    if (i < N) {
        const int val = bsumsc[blockIdx.x] + s[tid] - x;   // exclusive
        off[i] = val;
        cur[i] = val;
    }
    if (i == 0) off[N] = E;
}

__global__ __launch_bounds__(256) void scatter_kernel(
    const int* __restrict__ rows, const int* __restrict__ cols,
    int* __restrict__ cur, int* __restrict__ sc, int E) {
    const int e = blockIdx.x * 256 + threadIdx.x;
    if (e >= E) return;
    const int p = atomicAdd(&cur[rows[e]], 1);
    sc[p] = cols[e];
}

// ---------------------------------------------------------------------------
// Kernel 2: atomic-free aggregation.  One wave per destination node, lane=d.
// Per edge: ONE uint32 load from packed KV (k_d, v_d bf16 pair) = one 256B
// wave transaction; dot via shfl_xor in 16-lane head groups; registers-only
// accumulate; single plain store.
// ---------------------------------------------------------------------------
__global__ __launch_bounds__(256) void aggregate_kernel(
    const int* __restrict__ off, const int* __restrict__ sc,
    const float* __restrict__ Q, const unsigned int* __restrict__ KV,
    float* __restrict__ out, int N) {
    const int t = blockIdx.x * 256 + threadIdx.x;
    const int n = t >> 6;
    const int d = t & 63;
    if (n >= N) return;

    const int off0 = off[n];
    const int off1 = off[n + 1];
    const float q  = Q[(size_t)n * D + d];

    float accV = 0.f, accN = 0.f;
    int i = off0;
    for (; i + 1 < off1; i += 2) {
        const int c0 = sc[i];
        const int c1 = sc[i + 1];
        const unsigned int kv0 = KV[(size_t)c0 * 64 + d];
        const unsigned int kv1 = KV[(size_t)c1 * 64 + d];
        const float k0 = bf16_to_f32((unsigned short)(kv0 & 0xFFFF));
        const float v0 = bf16_to_f32((unsigned short)(kv0 >> 16));
        const float k1 = bf16_to_f32((unsigned short)(kv1 & 0xFFFF));
        const float v1 = bf16_to_f32((unsigned short)(kv1 >> 16));
        float p0 = q * k0;
        float p1 = q * k1;
        p0 += __shfl_xor(p0, 1);  p1 += __shfl_xor(p1, 1);
        p0 += __shfl_xor(p0, 2);  p1 += __shfl_xor(p1, 2);
        p0 += __shfl_xor(p0, 4);  p1 += __shfl_xor(p1, 4);
        p0 += __shfl_xor(p0, 8);  p1 += __shfl_xor(p1, 8);
        const float e0 = __expf(fminf(fmaxf(p0, -10.f), 10.f));
        const float e1 = __expf(fminf(fmaxf(p1, -10.f), 10.f));
        accN += e0 + e1;
        accV = fmaf(e0, v0, accV);
        accV = fmaf(e1, v1, accV);
    }
    if (i < off1) {
        const int c0 = sc[i];
        const unsigned int kv0 = KV[(size_t)c0 * 64 + d];
        const float k0 = bf16_to_f32((unsigned short)(kv0 & 0xFFFF));
        const float v0 = bf16_to_f32((unsigned short)(kv0 >> 16));
        float p0 = q * k0;
        p0 += __shfl_xor(p0, 1);
        p0 += __shfl_xor(p0, 2);
        p0 += __shfl_xor(p0, 4);
        p0 += __shfl_xor(p0, 8);
        const float e0 = __expf(fminf(fmaxf(p0, -10.f), 10.f));
        accN += e0;
        accV = fmaf(e0, v0, accV);
    }
    out[(size_t)n * D + d] = accV / (accN + 1e-8f);
}

extern "C" void kernel_launch(void* const* d_in, const int* in_sizes, int n_in,
                              void* d_out, int out_size, void* d_ws, size_t ws_size,
                              hipStream_t stream) {
    const float* emb = (const float*)d_in[0];
    const float* Wq  = (const float*)d_in[1];
    const float* Wk  = (const float*)d_in[2];
    const float* Wv  = (const float*)d_in[3];
    const int*   w32 = (const int*)d_in[4];

    const int N  = in_sizes[0] / D;   // 100000
    const int E  = in_sizes[4] / 2;   // 800000
    const int NB = (N + 255) / 256;   // 391 (<= 1024)
    const size_t ND = (size_t)N * D;

    const int* rows = w32;            // validated r10: [2,E], rows = half 0
    const int* cols = w32 + E;

    // Workspace (~59 MB): Q f32 | KV bf16-interleaved | cnt | off | cur |
    // bsum | bsumsc | sc
    float*          ws  = (float*)d_ws;
    float*          Q   = ws;
    unsigned short* KV  = (unsigned short*)(ws + ND);       // 2*ND ushort
    int*   cnt    = (int*)(ws + 2 * ND);
    int*   off    = cnt + N;          // N+1
    int*   cur    = off + N + 1;
    int*   bsum   = cur + N;
    int*   bsumsc = bsum + NB;
    int*   sc     = bsumsc + NB;

    float* out = (float*)d_out;

    (void)hipMemsetAsync(cnt, 0, (size_t)N * sizeof(int), stream);

    // 1) QKV projection (register-tiled GEMM, packed bf16 KV output)
    qkv_kernel<<<(N + 63) / 64, 256, 0, stream>>>(emb, Wq, Wk, Wv, N, Q, KV);

    // 2) Counting sort of edges by destination
    histo_kernel<<<(E + 255) / 256, 256, 0, stream>>>(rows, cnt, E);
    block_sum_kernel<<<NB, 256, 0, stream>>>(cnt, bsum, N);
    scan_bsum_kernel<<<1, 1024, 0, stream>>>(bsum, bsumsc, NB);
    block_scan_kernel<<<NB, 256, 0, stream>>>(cnt, bsumsc, off, cur, N, E);
    scatter_kernel<<<(E + 255) / 256, 256, 0, stream>>>(rows, cols, cur, sc, E);

    // 3) Atomic-free aggregation: one wave per node, one gather per edge
    aggregate_kernel<<<((size_t)N * 64 + 255) / 256, 256, 0, stream>>>(
        off, sc, Q, (const unsigned int*)KV, out, N);
}

// Round 17
// 255.490 us; speedup vs baseline: 1.8127x; 1.0641x over previous
//
#include <hip/hip_runtime.h>
#include <math.h>

// Structural constants (from reference code): D=64, H=4, dh=16.
constexpr int D  = 64;
constexpr int H  = 4;

// ---------------------------------------------------------------------------
// R16 FAILED by one bf16 ulp: absmax 0.11328 vs 0.113125.  Cause: bf16-
// quantized emb AND W as MFMA inputs added score error on BOTH sides of the
// QK dot (r15 had exact fp32 Q).  R17: split-precision MFMA — x = hi + lo
// (both bf16), A*B ~= Ah*Bh + Ah*Bl + Al*Bh (3 MFMAs, O(2^-16) rel error) ->
// r15-level accuracy (absmax ~0.055) at MFMA speed.  W pre-split into hi/lo
// fragment arrays (48 KB); A split in-register.  Keeps r16's 4-wide
// aggregate unroll (precision-inert).
// Layouts (verified learn_hip m89/m120): A[m=lane&15][k=(lane>>4)*8+j],
// B[k=(lane>>4)*8+j][n=lane&15], C/D col=lane&15 row=(lane>>4)*4+reg.
// ---------------------------------------------------------------------------

typedef __attribute__((ext_vector_type(8))) short bf16x8;
typedef __attribute__((ext_vector_type(4))) float f32x4;

__device__ __forceinline__ unsigned short f32_to_bf16(float f) {
    const unsigned int u = __float_as_uint(f);
    return (unsigned short)((u + 0x7FFFu + ((u >> 16) & 1u)) >> 16);  // RNE
}
__device__ __forceinline__ float bf16_to_f32(unsigned short h) {
    return __uint_as_float(((unsigned int)h) << 16);
}

// ---------------------------------------------------------------------------
// Kernel 0: pre-split W into hi/lo MFMA B-fragment order.
// idx -> [mt][ct][ks][lane l][j]:  W_mt[ks*32+(l>>4)*8+j][ct*16+(l&15)]
// hi = bf16(w), lo = bf16(w - hi).  2 x 24 KB.
// ---------------------------------------------------------------------------
__global__ __launch_bounds__(256) void prep_w_kernel(
    const float* __restrict__ Wq, const float* __restrict__ Wk,
    const float* __restrict__ Wv,
    unsigned short* __restrict__ WfH, unsigned short* __restrict__ WfL) {
    const float* W[3] = {Wq, Wk, Wv};
    for (int idx = threadIdx.x; idx < 3 * 4 * 2 * 64 * 8; idx += 256) {
        const int j  = idx & 7;
        const int l  = (idx >> 3) & 63;
        const int ks = (idx >> 9) & 1;
        const int ct = (idx >> 10) & 3;
        const int mt = idx >> 12;
        const int krow = ks * 32 + (l >> 4) * 8 + j;
        const int col  = ct * 16 + (l & 15);
        const float w  = W[mt][krow * 64 + col];
        const unsigned short h = f32_to_bf16(w);
        WfH[idx] = h;
        WfL[idx] = f32_to_bf16(w - bf16_to_f32(h));
    }
}

// ---------------------------------------------------------------------------
// Kernel 1: QKV projection via split-precision MFMA.  Block = 4 waves; wave =
// 16 nodes x 64 cols x 3 matrices = 72 MFMAs.  No LDS.  Outputs: Q fp32,
// KV bf16 interleaved pairs [k_d, v_d] (one uint32 per dim).
// ---------------------------------------------------------------------------
__global__ __launch_bounds__(256) void qkv_kernel(
    const float* __restrict__ emb,
    const unsigned short* __restrict__ WfH,
    const unsigned short* __restrict__ WfL,
    int N, float* __restrict__ Q, unsigned int* __restrict__ KV) {
    const int wv = threadIdx.x >> 6;
    const int l  = threadIdx.x & 63;
    const int qd = l >> 4;              // quad 0..3
    const int m  = l & 15;
    const int n0 = blockIdx.x * 64 + wv * 16;

    // A fragments, split hi/lo: k = ks*32 + qd*8 + j
    bf16x8 aH[2], aL[2];
    {
        int node = n0 + m;
        if (node >= N) node = N - 1;             // clamp; stores guarded below
        const float4* ep = (const float4*)(emb + (size_t)node * 64);
#pragma unroll
        for (int ks = 0; ks < 2; ++ks) {
            const float4 a0 = ep[ks * 8 + qd * 2 + 0];
            const float4 a1 = ep[ks * 8 + qd * 2 + 1];
            const float f[8] = {a0.x, a0.y, a0.z, a0.w, a1.x, a1.y, a1.z, a1.w};
            bf16x8 fh, fl;
#pragma unroll
            for (int j = 0; j < 8; ++j) {
                const unsigned short h = f32_to_bf16(f[j]);
                fh[j] = (short)h;
                fl[j] = (short)f32_to_bf16(f[j] - bf16_to_f32(h));
            }
            aH[ks] = fh;
            aL[ks] = fl;
        }
    }

    f32x4 acc[3][4];
#pragma unroll
    for (int mt = 0; mt < 3; ++mt)
#pragma unroll
        for (int ct = 0; ct < 4; ++ct) acc[mt][ct] = (f32x4){0.f, 0.f, 0.f, 0.f};

    const uint4* wfh = (const uint4*)WfH;   // 16 B per lane per fragment
    const uint4* wfl = (const uint4*)WfL;
#pragma unroll
    for (int mt = 0; mt < 3; ++mt) {
#pragma unroll
        for (int ct = 0; ct < 4; ++ct) {
#pragma unroll
            for (int ks = 0; ks < 2; ++ks) {
                const int fi = ((mt * 4 + ct) * 2 + ks) * 64 + l;
                const uint4 bh_raw = wfh[fi];
                const uint4 bl_raw = wfl[fi];
                bf16x8 bh, bl;
                memcpy(&bh, &bh_raw, 16);
                memcpy(&bl, &bl_raw, 16);
                acc[mt][ct] = __builtin_amdgcn_mfma_f32_16x16x32_bf16(
                    aH[ks], bh, acc[mt][ct], 0, 0, 0);
                acc[mt][ct] = __builtin_amdgcn_mfma_f32_16x16x32_bf16(
                    aH[ks], bl, acc[mt][ct], 0, 0, 0);
                acc[mt][ct] = __builtin_amdgcn_mfma_f32_16x16x32_bf16(
                    aL[ks], bh, acc[mt][ct], 0, 0, 0);
            }
        }
    }

    // Epilogue: D row = qd*4 + r, col = ct*16 + m.
#pragma unroll
    for (int r = 0; r < 4; ++r) {
        const int node = n0 + qd * 4 + r;
        if (node < N) {
#pragma unroll
            for (int ct = 0; ct < 4; ++ct) {
                Q[(size_t)node * 64 + ct * 16 + m] = acc[0][ct][r];
                const unsigned int kv =
                    (unsigned int)f32_to_bf16(acc[1][ct][r]) |
                    ((unsigned int)f32_to_bf16(acc[2][ct][r]) << 16);
                KV[(size_t)node * 64 + ct * 16 + m] = kv;
            }
        }
    }
}

// --- Counting sort: histogram -> block sums -> scan -> block scan -> scatter

__global__ __launch_bounds__(256) void histo_kernel(
    const int* __restrict__ rows, int* __restrict__ cnt, int E) {
    const int e = blockIdx.x * 256 + threadIdx.x;
    if (e < E) atomicAdd(&cnt[rows[e]], 1);
}

__global__ __launch_bounds__(256) void block_sum_kernel(
    const int* __restrict__ cnt, int* __restrict__ bsum, int N) {
    __shared__ int s[256];
    const int tid = threadIdx.x;
    const int i   = blockIdx.x * 256 + tid;
    s[tid] = (i < N) ? cnt[i] : 0;
    __syncthreads();
    for (int st = 128; st > 0; st >>= 1) {
        if (tid < st) s[tid] += s[tid + st];
        __syncthreads();
    }
    if (tid == 0) bsum[blockIdx.x] = s[0];
}

__global__ __launch_bounds__(1024) void scan_bsum_kernel(
    const int* __restrict__ bsum, int* __restrict__ bsumsc, int NB) {
    __shared__ int s[1024];
    const int tid = threadIdx.x;
    const int x   = (tid < NB) ? bsum[tid] : 0;
    s[tid] = x;
    __syncthreads();
    for (int offs = 1; offs < 1024; offs <<= 1) {
        int v = 0;
        if (tid >= offs) v = s[tid - offs];
        __syncthreads();
        if (tid >= offs) s[tid] += v;
        __syncthreads();
    }
    if (tid < NB) bsumsc[tid] = s[tid] - x;   // exclusive
}

__global__ __launch_bounds__(256) void block_scan_kernel(
    const int* __restrict__ cnt, const int* __restrict__ bsumsc,
    int* __restrict__ off, int* __restrict__ cur, int N, int E) {
    __shared__ int s[256];
    const int tid = threadIdx.x;
    const int i   = blockIdx.x * 256 + tid;
    const int x   = (i < N) ? cnt[i] : 0;
    s[tid] = x;
    __syncthreads();
    for (int offs = 1; offs < 256; offs <<= 1) {
        int v = 0;
        if (tid >= offs) v = s[tid - offs];
        __syncthreads();
        if (tid >= offs) s[tid] += v;
        __syncthreads();
    }
    if (i < N) {
        const int val = bsumsc[blockIdx.x] + s[tid] - x;   // exclusive
        off[i] = val;
        cur[i] = val;
    }
    if (i == 0) off[N] = E;
}

__global__ __launch_bounds__(256) void scatter_kernel(
    const int* __restrict__ rows, const int* __restrict__ cols,
    int* __restrict__ cur, int* __restrict__ sc, int E) {
    const int e = blockIdx.x * 256 + threadIdx.x;
    if (e >= E) return;
    const int p = atomicAdd(&cur[rows[e]], 1);
    sc[p] = cols[e];
}

// ---------------------------------------------------------------------------
// Kernel 2: atomic-free aggregation, 4-wide unrolled.  One wave per node,
// lane = dim; 4 independent KV gathers in flight; dot via shfl_xor in 16-lane
// head groups; registers-only accumulate; one plain store.
// ---------------------------------------------------------------------------
__global__ __launch_bounds__(256) void aggregate_kernel(
    const int* __restrict__ off, const int* __restrict__ sc,
    const float* __restrict__ Q, const unsigned int* __restrict__ KV,
    float* __restrict__ out, int N) {
    const int t = blockIdx.x * 256 + threadIdx.x;
    const int n = t >> 6;
    const int d = t & 63;
    if (n >= N) return;

    const int off0 = off[n];
    const int off1 = off[n + 1];
    const float q  = Q[(size_t)n * D + d];

    float accV = 0.f, accN = 0.f;
    int i = off0;
    for (; i + 3 < off1; i += 4) {
        const int c0 = sc[i];
        const int c1 = sc[i + 1];
        const int c2 = sc[i + 2];
        const int c3 = sc[i + 3];
        const unsigned int kv0 = KV[(size_t)c0 * 64 + d];
        const unsigned int kv1 = KV[(size_t)c1 * 64 + d];
        const unsigned int kv2 = KV[(size_t)c2 * 64 + d];
        const unsigned int kv3 = KV[(size_t)c3 * 64 + d];
        float p0 = q * bf16_to_f32((unsigned short)(kv0 & 0xFFFF));
        float p1 = q * bf16_to_f32((unsigned short)(kv1 & 0xFFFF));
        float p2 = q * bf16_to_f32((unsigned short)(kv2 & 0xFFFF));
        float p3 = q * bf16_to_f32((unsigned short)(kv3 & 0xFFFF));
        p0 += __shfl_xor(p0, 1);  p1 += __shfl_xor(p1, 1);
        p2 += __shfl_xor(p2, 1);  p3 += __shfl_xor(p3, 1);
        p0 += __shfl_xor(p0, 2);  p1 += __shfl_xor(p1, 2);
        p2 += __shfl_xor(p2, 2);  p3 += __shfl_xor(p3, 2);
        p0 += __shfl_xor(p0, 4);  p1 += __shfl_xor(p1, 4);
        p2 += __shfl_xor(p2, 4);  p3 += __shfl_xor(p3, 4);
        p0 += __shfl_xor(p0, 8);  p1 += __shfl_xor(p1, 8);
        p2 += __shfl_xor(p2, 8);  p3 += __shfl_xor(p3, 8);
        const float e0 = __expf(fminf(fmaxf(p0, -10.f), 10.f));
        const float e1 = __expf(fminf(fmaxf(p1, -10.f), 10.f));
        const float e2 = __expf(fminf(fmaxf(p2, -10.f), 10.f));
        const float e3 = __expf(fminf(fmaxf(p3, -10.f), 10.f));
        accN += (e0 + e1) + (e2 + e3);
        accV = fmaf(e0, bf16_to_f32((unsigned short)(kv0 >> 16)), accV);
        accV = fmaf(e1, bf16_to_f32((unsigned short)(kv1 >> 16)), accV);
        accV = fmaf(e2, bf16_to_f32((unsigned short)(kv2 >> 16)), accV);
        accV = fmaf(e3, bf16_to_f32((unsigned short)(kv3 >> 16)), accV);
    }
    for (; i < off1; ++i) {
        const int c0 = sc[i];
        const unsigned int kv0 = KV[(size_t)c0 * 64 + d];
        float p0 = q * bf16_to_f32((unsigned short)(kv0 & 0xFFFF));
        p0 += __shfl_xor(p0, 1);
        p0 += __shfl_xor(p0, 2);
        p0 += __shfl_xor(p0, 4);
        p0 += __shfl_xor(p0, 8);
        const float e0 = __expf(fminf(fmaxf(p0, -10.f), 10.f));
        accN += e0;
        accV = fmaf(e0, bf16_to_f32((unsigned short)(kv0 >> 16)), accV);
    }
    out[(size_t)n * D + d] = accV / (accN + 1e-8f);
}

extern "C" void kernel_launch(void* const* d_in, const int* in_sizes, int n_in,
                              void* d_out, int out_size, void* d_ws, size_t ws_size,
                              hipStream_t stream) {
    const float* emb = (const float*)d_in[0];
    const float* Wq  = (const float*)d_in[1];
    const float* Wk  = (const float*)d_in[2];
    const float* Wv  = (const float*)d_in[3];
    const int*   w32 = (const int*)d_in[4];

    const int N  = in_sizes[0] / D;   // 100000
    const int E  = in_sizes[4] / 2;   // 800000
    const int NB = (N + 255) / 256;   // 391 (<= 1024)
    const size_t ND = (size_t)N * D;

    const int* rows = w32;            // validated r10: [2,E], rows = half 0
    const int* cols = w32 + E;

    // Workspace (~59 MB): Q f32 | KV bf16-pairs | cnt | off | cur | bsum |
    // bsumsc | sc | WfH | WfL
    float*          ws  = (float*)d_ws;
    float*          Q   = ws;
    unsigned int*   KV  = (unsigned int*)(ws + ND);         // ND uint32
    int*   cnt    = (int*)(ws + 2 * ND);
    int*   off    = cnt + N;          // N+1
    int*   cur    = off + N + 1;
    int*   bsum   = cur + N;
    int*   bsumsc = bsum + NB;
    int*   sc     = bsumsc + NB;
    unsigned short* WfH = (unsigned short*)(sc + E);        // 24 KB
    unsigned short* WfL = WfH + 12288;                      // 24 KB

    float* out = (float*)d_out;

    (void)hipMemsetAsync(cnt, 0, (size_t)N * sizeof(int), stream);

    // 0) W -> hi/lo MFMA fragment order (48 KB, single block)
    prep_w_kernel<<<1, 256, 0, stream>>>(Wq, Wk, Wv, WfH, WfL);

    // 1) QKV projection (split-precision MFMA, LDS-free)
    qkv_kernel<<<(N + 63) / 64, 256, 0, stream>>>(emb, WfH, WfL, N, Q, KV);

    // 2) Counting sort of edges by destination
    histo_kernel<<<(E + 255) / 256, 256, 0, stream>>>(rows, cnt, E);
    block_sum_kernel<<<NB, 256, 0, stream>>>(cnt, bsum, N);
    scan_bsum_kernel<<<1, 1024, 0, stream>>>(bsum, bsumsc, NB);
    block_scan_kernel<<<NB, 256, 0, stream>>>(cnt, bsumsc, off, cur, N, E);
    scatter_kernel<<<(E + 255) / 256, 256, 0, stream>>>(rows, cols, cur, sc, E);

    // 3) Atomic-free aggregation: one wave per node, 4 gathers in flight
    aggregate_kernel<<<((size_t)N * 64 + 255) / 256, 256, 0, stream>>>(
        off, sc, Q, KV, out, N);
}

// Round 18
// 245.224 us; speedup vs baseline: 1.8885x; 1.0419x over previous
//
#include <hip/hip_runtime.h>
#include <math.h>

// Structural constants (from reference code): D=64, H=4, dh=16.
constexpr int D  = 64;
constexpr int H  = 4;

// ---------------------------------------------------------------------------
// R17: 255us, absmax 0.0547 (split-precision MFMA exact as predicted).
// aggregate 60us = MLP-limited: 20 waves/CU x 4 outstanding x 64B / 600ns
// ~= 2.2 TB/s == measured.  R18: (1) aggregate 8-wide unroll -> 8 gathers in
// flight (Little's law: ~2x); (2) qkv Wf fragments staged in LDS (48KB) --
// kills 600MB of L1-thrashing broadcast reads.
// Layouts (verified learn_hip m89/m120): A[m=lane&15][k=(lane>>4)*8+j],
// B[k=(lane>>4)*8+j][n=lane&15], C/D col=lane&15 row=(lane>>4)*4+reg.
// ---------------------------------------------------------------------------

typedef __attribute__((ext_vector_type(8))) short bf16x8;
typedef __attribute__((ext_vector_type(4))) float f32x4;

__device__ __forceinline__ unsigned short f32_to_bf16(float f) {
    const unsigned int u = __float_as_uint(f);
    return (unsigned short)((u + 0x7FFFu + ((u >> 16) & 1u)) >> 16);  // RNE
}
__device__ __forceinline__ float bf16_to_f32(unsigned short h) {
    return __uint_as_float(((unsigned int)h) << 16);
}

// ---------------------------------------------------------------------------
// Kernel 0: pre-split W into hi/lo MFMA B-fragment order.
// idx -> [mt][ct][ks][lane l][j]:  W_mt[ks*32+(l>>4)*8+j][ct*16+(l&15)]
// hi = bf16(w), lo = bf16(w - hi).  2 x 24 KB.
// ---------------------------------------------------------------------------
__global__ __launch_bounds__(256) void prep_w_kernel(
    const float* __restrict__ Wq, const float* __restrict__ Wk,
    const float* __restrict__ Wv,
    unsigned short* __restrict__ WfH, unsigned short* __restrict__ WfL) {
    const float* W[3] = {Wq, Wk, Wv};
    for (int idx = threadIdx.x; idx < 3 * 4 * 2 * 64 * 8; idx += 256) {
        const int j  = idx & 7;
        const int l  = (idx >> 3) & 63;
        const int ks = (idx >> 9) & 1;
        const int ct = (idx >> 10) & 3;
        const int mt = idx >> 12;
        const int krow = ks * 32 + (l >> 4) * 8 + j;
        const int col  = ct * 16 + (l & 15);
        const float w  = W[mt][krow * 64 + col];
        const unsigned short h = f32_to_bf16(w);
        WfH[idx] = h;
        WfL[idx] = f32_to_bf16(w - bf16_to_f32(h));
    }
}

// ---------------------------------------------------------------------------
// Kernel 1: QKV projection via split-precision MFMA.  Block = 4 waves; wave =
// 16 nodes x 64 cols x 3 matrices = 72 MFMAs.  Wf hi/lo staged in LDS once
// per block (48 KB) -> ds_read_b128 fragment loads, no L1 thrash.
// Outputs: Q fp32, KV bf16 interleaved pairs [k_d, v_d] (one uint32/dim).
// ---------------------------------------------------------------------------
__global__ __launch_bounds__(256) void qkv_kernel(
    const float* __restrict__ emb,
    const unsigned short* __restrict__ WfH,
    const unsigned short* __restrict__ WfL,
    int N, float* __restrict__ Q, unsigned int* __restrict__ KV) {
    __shared__ unsigned short sH[12288];   // 24 KB
    __shared__ unsigned short sL[12288];   // 24 KB
    const int tid = threadIdx.x;

    // Stage both fragment arrays: 3072 uint4 total, 12 per thread.
    {
        const uint4* gh = (const uint4*)WfH;
        const uint4* gl = (const uint4*)WfL;
        uint4* shh = (uint4*)sH;
        uint4* sll = (uint4*)sL;
        for (int k = tid; k < 1536; k += 256) {
            shh[k] = gh[k];
            sll[k] = gl[k];
        }
    }
    __syncthreads();

    const int wv = tid >> 6;
    const int l  = tid & 63;
    const int qd = l >> 4;              // quad 0..3
    const int m  = l & 15;
    const int n0 = blockIdx.x * 64 + wv * 16;

    // A fragments, split hi/lo: k = ks*32 + qd*8 + j
    bf16x8 aH[2], aL[2];
    {
        int node = n0 + m;
        if (node >= N) node = N - 1;             // clamp; stores guarded below
        const float4* ep = (const float4*)(emb + (size_t)node * 64);
#pragma unroll
        for (int ks = 0; ks < 2; ++ks) {
            const float4 a0 = ep[ks * 8 + qd * 2 + 0];
            const float4 a1 = ep[ks * 8 + qd * 2 + 1];
            const float f[8] = {a0.x, a0.y, a0.z, a0.w, a1.x, a1.y, a1.z, a1.w};
            bf16x8 fh, fl;
#pragma unroll
            for (int j = 0; j < 8; ++j) {
                const unsigned short h = f32_to_bf16(f[j]);
                fh[j] = (short)h;
                fl[j] = (short)f32_to_bf16(f[j] - bf16_to_f32(h));
            }
            aH[ks] = fh;
            aL[ks] = fl;
        }
    }

    f32x4 acc[3][4];
#pragma unroll
    for (int mt = 0; mt < 3; ++mt)
#pragma unroll
        for (int ct = 0; ct < 4; ++ct) acc[mt][ct] = (f32x4){0.f, 0.f, 0.f, 0.f};

#pragma unroll
    for (int mt = 0; mt < 3; ++mt) {
#pragma unroll
        for (int ct = 0; ct < 4; ++ct) {
#pragma unroll
            for (int ks = 0; ks < 2; ++ks) {
                const int fi = (((mt * 4 + ct) * 2 + ks) * 64 + l) * 8;
                bf16x8 bh = *(const bf16x8*)&sH[fi];
                bf16x8 bl = *(const bf16x8*)&sL[fi];
                acc[mt][ct] = __builtin_amdgcn_mfma_f32_16x16x32_bf16(
                    aH[ks], bh, acc[mt][ct], 0, 0, 0);
                acc[mt][ct] = __builtin_amdgcn_mfma_f32_16x16x32_bf16(
                    aH[ks], bl, acc[mt][ct], 0, 0, 0);
                acc[mt][ct] = __builtin_amdgcn_mfma_f32_16x16x32_bf16(
                    aL[ks], bh, acc[mt][ct], 0, 0, 0);
            }
        }
    }

    // Epilogue: D row = qd*4 + r, col = ct*16 + m.
#pragma unroll
    for (int r = 0; r < 4; ++r) {
        const int node = n0 + qd * 4 + r;
        if (node < N) {
#pragma unroll
            for (int ct = 0; ct < 4; ++ct) {
                Q[(size_t)node * 64 + ct * 16 + m] = acc[0][ct][r];
                const unsigned int kv =
                    (unsigned int)f32_to_bf16(acc[1][ct][r]) |
                    ((unsigned int)f32_to_bf16(acc[2][ct][r]) << 16);
                KV[(size_t)node * 64 + ct * 16 + m] = kv;
            }
        }
    }
}

// --- Counting sort: histogram -> block sums -> scan -> block scan -> scatter

__global__ __launch_bounds__(256) void histo_kernel(
    const int* __restrict__ rows, int* __restrict__ cnt, int E) {
    const int e = blockIdx.x * 256 + threadIdx.x;
    if (e < E) atomicAdd(&cnt[rows[e]], 1);
}

__global__ __launch_bounds__(256) void block_sum_kernel(
    const int* __restrict__ cnt, int* __restrict__ bsum, int N) {
    __shared__ int s[256];
    const int tid = threadIdx.x;
    const int i   = blockIdx.x * 256 + tid;
    s[tid] = (i < N) ? cnt[i] : 0;
    __syncthreads();
    for (int st = 128; st > 0; st >>= 1) {
        if (tid < st) s[tid] += s[tid + st];
        __syncthreads();
    }
    if (tid == 0) bsum[blockIdx.x] = s[0];
}

__global__ __launch_bounds__(1024) void scan_bsum_kernel(
    const int* __restrict__ bsum, int* __restrict__ bsumsc, int NB) {
    __shared__ int s[1024];
    const int tid = threadIdx.x;
    const int x   = (tid < NB) ? bsum[tid] : 0;
    s[tid] = x;
    __syncthreads();
    for (int offs = 1; offs < 1024; offs <<= 1) {
        int v = 0;
        if (tid >= offs) v = s[tid - offs];
        __syncthreads();
        if (tid >= offs) s[tid] += v;
        __syncthreads();
    }
    if (tid < NB) bsumsc[tid] = s[tid] - x;   // exclusive
}

__global__ __launch_bounds__(256) void block_scan_kernel(
    const int* __restrict__ cnt, const int* __restrict__ bsumsc,
    int* __restrict__ off, int* __restrict__ cur, int N, int E) {
    __shared__ int s[256];
    const int tid = threadIdx.x;
    const int i   = blockIdx.x * 256 + tid;
    const int x   = (i < N) ? cnt[i] : 0;
    s[tid] = x;
    __syncthreads();
    for (int offs = 1; offs < 256; offs <<= 1) {
        int v = 0;
        if (tid >= offs) v = s[tid - offs];
        __syncthreads();
        if (tid >= offs) s[tid] += v;
        __syncthreads();
    }
    if (i < N) {
        const int val = bsumsc[blockIdx.x] + s[tid] - x;   // exclusive
        off[i] = val;
        cur[i] = val;
    }
    if (i == 0) off[N] = E;
}

__global__ __launch_bounds__(256) void scatter_kernel(
    const int* __restrict__ rows, const int* __restrict__ cols,
    int* __restrict__ cur, int* __restrict__ sc, int E) {
    const int e = blockIdx.x * 256 + threadIdx.x;
    if (e >= E) return;
    const int p = atomicAdd(&cur[rows[e]], 1);
    sc[p] = cols[e];
}

// ---------------------------------------------------------------------------
// Kernel 2: atomic-free aggregation, 8-wide unrolled (8 gathers in flight),
// 4-wide mid loop, scalar tail.  One wave per node, lane = dim; dot via
// shfl_xor in 16-lane head groups; registers-only accumulate; one store.
// ---------------------------------------------------------------------------
__global__ __launch_bounds__(256) void aggregate_kernel(
    const int* __restrict__ off, const int* __restrict__ sc,
    const float* __restrict__ Q, const unsigned int* __restrict__ KV,
    float* __restrict__ out, int N) {
    const int t = blockIdx.x * 256 + threadIdx.x;
    const int n = t >> 6;
    const int d = t & 63;
    if (n >= N) return;

    const int off0 = off[n];
    const int off1 = off[n + 1];
    const float q  = Q[(size_t)n * D + d];

    float accV = 0.f, accN = 0.f;
    int i = off0;

    for (; i + 7 < off1; i += 8) {
        unsigned int kv[8];
#pragma unroll
        for (int j = 0; j < 8; ++j) kv[j] = KV[(size_t)sc[i + j] * 64 + d];
        float p[8];
#pragma unroll
        for (int j = 0; j < 8; ++j)
            p[j] = q * bf16_to_f32((unsigned short)(kv[j] & 0xFFFF));
#pragma unroll
        for (int j = 0; j < 8; ++j) {
            p[j] += __shfl_xor(p[j], 1);
            p[j] += __shfl_xor(p[j], 2);
            p[j] += __shfl_xor(p[j], 4);
            p[j] += __shfl_xor(p[j], 8);
        }
#pragma unroll
        for (int j = 0; j < 8; ++j) {
            const float e = __expf(fminf(fmaxf(p[j], -10.f), 10.f));
            accN += e;
            accV = fmaf(e, bf16_to_f32((unsigned short)(kv[j] >> 16)), accV);
        }
    }
    for (; i + 3 < off1; i += 4) {
        unsigned int kv[4];
#pragma unroll
        for (int j = 0; j < 4; ++j) kv[j] = KV[(size_t)sc[i + j] * 64 + d];
        float p[4];
#pragma unroll
        for (int j = 0; j < 4; ++j)
            p[j] = q * bf16_to_f32((unsigned short)(kv[j] & 0xFFFF));
#pragma unroll
        for (int j = 0; j < 4; ++j) {
            p[j] += __shfl_xor(p[j], 1);
            p[j] += __shfl_xor(p[j], 2);
            p[j] += __shfl_xor(p[j], 4);
            p[j] += __shfl_xor(p[j], 8);
        }
#pragma unroll
        for (int j = 0; j < 4; ++j) {
            const float e = __expf(fminf(fmaxf(p[j], -10.f), 10.f));
            accN += e;
            accV = fmaf(e, bf16_to_f32((unsigned short)(kv[j] >> 16)), accV);
        }
    }
    for (; i < off1; ++i) {
        const unsigned int kv0 = KV[(size_t)sc[i] * 64 + d];
        float p0 = q * bf16_to_f32((unsigned short)(kv0 & 0xFFFF));
        p0 += __shfl_xor(p0, 1);
        p0 += __shfl_xor(p0, 2);
        p0 += __shfl_xor(p0, 4);
        p0 += __shfl_xor(p0, 8);
        const float e0 = __expf(fminf(fmaxf(p0, -10.f), 10.f));
        accN += e0;
        accV = fmaf(e0, bf16_to_f32((unsigned short)(kv0 >> 16)), accV);
    }
    out[(size_t)n * D + d] = accV / (accN + 1e-8f);
}

extern "C" void kernel_launch(void* const* d_in, const int* in_sizes, int n_in,
                              void* d_out, int out_size, void* d_ws, size_t ws_size,
                              hipStream_t stream) {
    const float* emb = (const float*)d_in[0];
    const float* Wq  = (const float*)d_in[1];
    const float* Wk  = (const float*)d_in[2];
    const float* Wv  = (const float*)d_in[3];
    const int*   w32 = (const int*)d_in[4];

    const int N  = in_sizes[0] / D;   // 100000
    const int E  = in_sizes[4] / 2;   // 800000
    const int NB = (N + 255) / 256;   // 391 (<= 1024)
    const size_t ND = (size_t)N * D;

    const int* rows = w32;            // validated r10: [2,E], rows = half 0
    const int* cols = w32 + E;

    // Workspace (~59 MB): Q f32 | KV bf16-pairs | cnt | off | cur | bsum |
    // bsumsc | sc | WfH | WfL
    float*          ws  = (float*)d_ws;
    float*          Q   = ws;
    unsigned int*   KV  = (unsigned int*)(ws + ND);         // ND uint32
    int*   cnt    = (int*)(ws + 2 * ND);
    int*   off    = cnt + N;          // N+1
    int*   cur    = off + N + 1;
    int*   bsum   = cur + N;
    int*   bsumsc = bsum + NB;
    int*   sc     = bsumsc + NB;
    unsigned short* WfH = (unsigned short*)(sc + E);        // 24 KB
    unsigned short* WfL = WfH + 12288;                      // 24 KB

    float* out = (float*)d_out;

    (void)hipMemsetAsync(cnt, 0, (size_t)N * sizeof(int), stream);

    // 0) W -> hi/lo MFMA fragment order (48 KB, single block)
    prep_w_kernel<<<1, 256, 0, stream>>>(Wq, Wk, Wv, WfH, WfL);

    // 1) QKV projection (split-precision MFMA, Wf in LDS)
    qkv_kernel<<<(N + 63) / 64, 256, 0, stream>>>(emb, WfH, WfL, N, Q, KV);

    // 2) Counting sort of edges by destination
    histo_kernel<<<(E + 255) / 256, 256, 0, stream>>>(rows, cnt, E);
    block_sum_kernel<<<NB, 256, 0, stream>>>(cnt, bsum, N);
    scan_bsum_kernel<<<1, 1024, 0, stream>>>(bsum, bsumsc, NB);
    block_scan_kernel<<<NB, 256, 0, stream>>>(cnt, bsumsc, off, cur, N, E);
    scatter_kernel<<<(E + 255) / 256, 256, 0, stream>>>(rows, cols, cur, sc, E);

    // 3) Atomic-free aggregation: one wave per node, 8 gathers in flight
    aggregate_kernel<<<((size_t)N * 64 + 255) / 256, 256, 0, stream>>>(
        off, sc, Q, KV, out, N);
}

// Round 19
// 238.056 us; speedup vs baseline: 1.9454x; 1.0301x over previous
//
#include <hip/hip_runtime.h>
#include <math.h>

constexpr int D = 64;
constexpr int H = 4;

// ---------------------------------------------------------------------------
// R18: 245us; aggregate 55.7us VALU-bound (65% busy, ~20 inst/edge, one edge
// per wave-step).  R19: 2-edges-per-wave aggregate — lane = dim-PAIR (p=l&31),
// edge parity ep=l>>5; KV repacked as KVP[node][p] = {k2p|k2p+1, v2p|v2p+1};
// every exp/clamp/accN inst serves 2 edges; head reduction 3 shfl (8 lanes).
// qkv B-swizzle col map changed to 4m+ct so lanes hold ADJACENT output dims:
// Q stores dwordx4, KVP packs in-lane.  scan_bsum fused into block_scan.
// Layouts (verified learn_hip m89/m120): A[m=lane&15][k=(lane>>4)*8+j],
// B[k=(lane>>4)*8+j][n=lane&15], C/D col=lane&15 row=(lane>>4)*4+reg.
// ---------------------------------------------------------------------------

typedef __attribute__((ext_vector_type(8))) short bf16x8;
typedef __attribute__((ext_vector_type(4))) float f32x4;

__device__ __forceinline__ unsigned short f32_to_bf16(float f) {
    const unsigned int u = __float_as_uint(f);
    return (unsigned short)((u + 0x7FFFu + ((u >> 16) & 1u)) >> 16);  // RNE
}
__device__ __forceinline__ float bf16_to_f32(unsigned short h) {
    return __uint_as_float(((unsigned int)h) << 16);
}
__device__ __forceinline__ float bf16lo_f32(unsigned int w) {   // bits 0-15
    return __uint_as_float(w << 16);
}
__device__ __forceinline__ float bf16hi_f32(unsigned int w) {   // bits 16-31
    return __uint_as_float(w & 0xFFFF0000u);
}

// ---------------------------------------------------------------------------
// Kernel 0: pre-split W into hi/lo MFMA B-fragment order with PERMUTED column
// map: fragment (mt, ct, ks, lane l, j) <- W_mt[ks*32+(l>>4)*8+j][4*(l&15)+ct]
// so MFMA acc[mt][ct] at lane m holds ORIGINAL output col 4m+ct.
// ---------------------------------------------------------------------------
__global__ __launch_bounds__(256) void prep_w_kernel(
    const float* __restrict__ Wq, const float* __restrict__ Wk,
    const float* __restrict__ Wv,
    unsigned short* __restrict__ WfH, unsigned short* __restrict__ WfL) {
    const float* W[3] = {Wq, Wk, Wv};
    for (int idx = threadIdx.x; idx < 3 * 4 * 2 * 64 * 8; idx += 256) {
        const int j  = idx & 7;
        const int l  = (idx >> 3) & 63;
        const int ks = (idx >> 9) & 1;
        const int ct = (idx >> 10) & 3;
        const int mt = idx >> 12;
        const int krow = ks * 32 + (l >> 4) * 8 + j;
        const int col  = 4 * (l & 15) + ct;          // permuted column map
        const float w  = W[mt][krow * 64 + col];
        const unsigned short h = f32_to_bf16(w);
        WfH[idx] = h;
        WfL[idx] = f32_to_bf16(w - bf16_to_f32(h));
    }
}

// ---------------------------------------------------------------------------
// Kernel 1: QKV projection via split-precision MFMA (Ah*Bh + Ah*Bl + Al*Bh).
// Block = 4 waves; wave = 16 nodes.  Wf hi/lo staged in LDS (48 KB).
// Outputs: Q fp32 (dwordx4 per lane), KVP uint2 pairs (dwordx4 per lane).
// ---------------------------------------------------------------------------
__global__ __launch_bounds__(256) void qkv_kernel(
    const float* __restrict__ emb,
    const unsigned short* __restrict__ WfH,
    const unsigned short* __restrict__ WfL,
    int N, float* __restrict__ Q, unsigned int* __restrict__ KVP) {
    __shared__ unsigned short sH[12288];   // 24 KB
    __shared__ unsigned short sL[12288];   // 24 KB
    const int tid = threadIdx.x;

    {
        const uint4* gh = (const uint4*)WfH;
        const uint4* gl = (const uint4*)WfL;
        uint4* shh = (uint4*)sH;
        uint4* sll = (uint4*)sL;
        for (int k = tid; k < 1536; k += 256) {
            shh[k] = gh[k];
            sll[k] = gl[k];
        }
    }
    __syncthreads();

    const int wv = tid >> 6;
    const int l  = tid & 63;
    const int qd = l >> 4;              // quad 0..3
    const int m  = l & 15;
    const int n0 = blockIdx.x * 64 + wv * 16;

    // A fragments, split hi/lo: k = ks*32 + qd*8 + j
    bf16x8 aH[2], aL[2];
    {
        int node = n0 + m;
        if (node >= N) node = N - 1;
        const float4* ep = (const float4*)(emb + (size_t)node * 64);
#pragma unroll
        for (int ks = 0; ks < 2; ++ks) {
            const float4 a0 = ep[ks * 8 + qd * 2 + 0];
            const float4 a1 = ep[ks * 8 + qd * 2 + 1];
            const float f[8] = {a0.x, a0.y, a0.z, a0.w, a1.x, a1.y, a1.z, a1.w};
            bf16x8 fh, fl;
#pragma unroll
            for (int j = 0; j < 8; ++j) {
                const unsigned short h = f32_to_bf16(f[j]);
                fh[j] = (short)h;
                fl[j] = (short)f32_to_bf16(f[j] - bf16_to_f32(h));
            }
            aH[ks] = fh;
            aL[ks] = fl;
        }
    }

    f32x4 acc[3][4];
#pragma unroll
    for (int mt = 0; mt < 3; ++mt)
#pragma unroll
        for (int ct = 0; ct < 4; ++ct) acc[mt][ct] = (f32x4){0.f, 0.f, 0.f, 0.f};

#pragma unroll
    for (int mt = 0; mt < 3; ++mt) {
#pragma unroll
        for (int ct = 0; ct < 4; ++ct) {
#pragma unroll
            for (int ks = 0; ks < 2; ++ks) {
                const int fi = (((mt * 4 + ct) * 2 + ks) * 64 + l) * 8;
                bf16x8 bh = *(const bf16x8*)&sH[fi];
                bf16x8 bl = *(const bf16x8*)&sL[fi];
                acc[mt][ct] = __builtin_amdgcn_mfma_f32_16x16x32_bf16(
                    aH[ks], bh, acc[mt][ct], 0, 0, 0);
                acc[mt][ct] = __builtin_amdgcn_mfma_f32_16x16x32_bf16(
                    aH[ks], bl, acc[mt][ct], 0, 0, 0);
                acc[mt][ct] = __builtin_amdgcn_mfma_f32_16x16x32_bf16(
                    aL[ks], bh, acc[mt][ct], 0, 0, 0);
            }
        }
    }

    // Epilogue: lane holds original cols 4m+ct (ct=0..3), row = qd*4 + r.
#pragma unroll
    for (int r = 0; r < 4; ++r) {
        const int node = n0 + qd * 4 + r;
        if (node < N) {
            float4 oq;
            oq.x = acc[0][0][r]; oq.y = acc[0][1][r];
            oq.z = acc[0][2][r]; oq.w = acc[0][3][r];
            *(float4*)(Q + (size_t)node * 64 + 4 * m) = oq;

            uint4 kv;   // {kpack(4m,4m+1), vpack(..), kpack(4m+2,4m+3), vpack(..)}
            kv.x = (unsigned int)f32_to_bf16(acc[1][0][r]) |
                   ((unsigned int)f32_to_bf16(acc[1][1][r]) << 16);
            kv.y = (unsigned int)f32_to_bf16(acc[2][0][r]) |
                   ((unsigned int)f32_to_bf16(acc[2][1][r]) << 16);
            kv.z = (unsigned int)f32_to_bf16(acc[1][2][r]) |
                   ((unsigned int)f32_to_bf16(acc[1][3][r]) << 16);
            kv.w = (unsigned int)f32_to_bf16(acc[2][2][r]) |
                   ((unsigned int)f32_to_bf16(acc[2][3][r]) << 16);
            *(uint4*)(KVP + (size_t)node * 64 + 4 * m) = kv;   // uint2 idx 2m..2m+1
        }
    }
}

// --- Counting sort: histogram -> block sums -> block scan(+prefix) -> scatter

__global__ __launch_bounds__(256) void histo_kernel(
    const int* __restrict__ rows, int* __restrict__ cnt, int E) {
    const int e = blockIdx.x * 256 + threadIdx.x;
    if (e < E) atomicAdd(&cnt[rows[e]], 1);
}

__global__ __launch_bounds__(256) void block_sum_kernel(
    const int* __restrict__ cnt, int* __restrict__ bsum, int N) {
    __shared__ int s[256];
    const int tid = threadIdx.x;
    const int i   = blockIdx.x * 256 + tid;
    s[tid] = (i < N) ? cnt[i] : 0;
    __syncthreads();
    for (int st = 128; st > 0; st >>= 1) {
        if (tid < st) s[tid] += s[tid + st];
        __syncthreads();
    }
    if (tid == 0) bsum[blockIdx.x] = s[0];
}

// Per-chunk exclusive scan; global base computed IN-KERNEL from bsum.
__global__ __launch_bounds__(256) void block_scan_kernel(
    const int* __restrict__ cnt, const int* __restrict__ bsum,
    int* __restrict__ off, int* __restrict__ cur, int N, int E, int NB) {
    __shared__ int s[256];
    __shared__ int red[256];
    const int tid = threadIdx.x;
    const int bid = blockIdx.x;
    const int i   = bid * 256 + tid;

    // Global exclusive prefix of bsum for this block.
    int pacc = 0;
    for (int k = tid; k < NB; k += 256) {
        if (k < bid) pacc += bsum[k];
    }
    red[tid] = pacc;
    __syncthreads();
    for (int st = 128; st > 0; st >>= 1) {
        if (tid < st) red[tid] += red[tid + st];
        __syncthreads();
    }
    const int base = red[0];

    const int x = (i < N) ? cnt[i] : 0;
    s[tid] = x;
    __syncthreads();
    for (int offs = 1; offs < 256; offs <<= 1) {
        int v = 0;
        if (tid >= offs) v = s[tid - offs];
        __syncthreads();
        if (tid >= offs) s[tid] += v;
        __syncthreads();
    }
    if (i < N) {
        const int val = base + s[tid] - x;   // exclusive
        off[i] = val;
        cur[i] = val;
    }
    if (i == 0) off[N] = E;
}

__global__ __launch_bounds__(256) void scatter_kernel(
    const int* __restrict__ rows, const int* __restrict__ cols,
    int* __restrict__ cur, int* __restrict__ sc, int E) {
    const int e = blockIdx.x * 256 + threadIdx.x;
    if (e >= E) return;
    const int p = atomicAdd(&cur[rows[e]], 1);
    sc[p] = cols[e];
}

// ---------------------------------------------------------------------------
// Kernel 2: atomic-free aggregation, 2 edges per wave.
// lane l: p = l&31 (dim pair 2p,2p+1), ep = l>>5 (edge slot).
// Per pair-step: both halves process different edges; head reduction = 3
// shfl_xor over 8 lanes; final cross-half combine via shfl_xor(32).
// ---------------------------------------------------------------------------
__global__ __launch_bounds__(256) void aggregate_kernel(
    const int* __restrict__ off, const int* __restrict__ sc,
    const float* __restrict__ Q, const unsigned int* __restrict__ KVP,
    float* __restrict__ out, int N) {
    const int t = blockIdx.x * 256 + threadIdx.x;
    const int n = t >> 6;
    const int l = t & 63;
    if (n >= N) return;
    const int p  = l & 31;
    const int ep = l >> 5;

    const int off0 = off[n];
    const int off1 = off[n + 1];
    const float2 q2 = *(const float2*)(Q + (size_t)n * 64 + 2 * p);

    float accV0 = 0.f, accV1 = 0.f, accN = 0.f;
    int i = off0;

    // Main: 8 edges per iteration (4 pair-steps, 4 gathers in flight).
    for (; i + 7 < off1; i += 8) {
        int c[4];
        uint2 kv[4];
#pragma unroll
        for (int j = 0; j < 4; ++j) c[j] = sc[i + 2 * j + ep];
#pragma unroll
        for (int j = 0; j < 4; ++j)
            kv[j] = *(const uint2*)(KVP + (size_t)c[j] * 64 + 2 * p);
#pragma unroll
        for (int j = 0; j < 4; ++j) {
            float pp = q2.x * bf16lo_f32(kv[j].x);
            pp = fmaf(q2.y, bf16hi_f32(kv[j].x), pp);
            pp += __shfl_xor(pp, 1);
            pp += __shfl_xor(pp, 2);
            pp += __shfl_xor(pp, 4);
            const float e = __expf(fminf(fmaxf(pp, -10.f), 10.f));
            accN += e;
            accV0 = fmaf(e, bf16lo_f32(kv[j].y), accV0);
            accV1 = fmaf(e, bf16hi_f32(kv[j].y), accV1);
        }
    }
    // Tail: 2 edges per step with validity masking.
    for (; i < off1; i += 2) {
        const int idx   = i + ep;
        const bool ok   = idx < off1;
        const int c0    = sc[ok ? idx : off1 - 1];
        const uint2 kv0 = *(const uint2*)(KVP + (size_t)c0 * 64 + 2 * p);
        float pp = q2.x * bf16lo_f32(kv0.x);
        pp = fmaf(q2.y, bf16hi_f32(kv0.x), pp);
        pp += __shfl_xor(pp, 1);
        pp += __shfl_xor(pp, 2);
        pp += __shfl_xor(pp, 4);
        float e = __expf(fminf(fmaxf(pp, -10.f), 10.f));
        e = ok ? e : 0.f;
        accN += e;
        accV0 = fmaf(e, bf16lo_f32(kv0.y), accV0);
        accV1 = fmaf(e, bf16hi_f32(kv0.y), accV1);
    }

    // Combine the two edge-halves.
    accN  += __shfl_xor(accN, 32);
    accV0 += __shfl_xor(accV0, 32);
    accV1 += __shfl_xor(accV1, 32);

    if (l < 32) {
        const float inv = 1.f / (accN + 1e-8f);
        float2 o;
        o.x = accV0 * inv;
        o.y = accV1 * inv;
        *(float2*)(out + (size_t)n * 64 + 2 * p) = o;
    }
}

extern "C" void kernel_launch(void* const* d_in, const int* in_sizes, int n_in,
                              void* d_out, int out_size, void* d_ws, size_t ws_size,
                              hipStream_t stream) {
    const float* emb = (const float*)d_in[0];
    const float* Wq  = (const float*)d_in[1];
    const float* Wk  = (const float*)d_in[2];
    const float* Wv  = (const float*)d_in[3];
    const int*   w32 = (const int*)d_in[4];

    const int N  = in_sizes[0] / D;   // 100000
    const int E  = in_sizes[4] / 2;   // 800000
    const int NB = (N + 255) / 256;   // 391
    const size_t ND = (size_t)N * D;

    const int* rows = w32;            // validated r10: [2,E], rows = half 0
    const int* cols = w32 + E;

    // Workspace (~59 MB): Q f32 | KVP uint2-pairs | cnt | off | cur | bsum |
    // sc | WfH | WfL
    float*          ws  = (float*)d_ws;
    float*          Q   = ws;
    unsigned int*   KVP = (unsigned int*)(ws + ND);        // ND uint32
    int*   cnt  = (int*)(ws + 2 * ND);
    int*   off  = cnt + N;            // N+1
    int*   cur  = off + N + 1;
    int*   bsum = cur + N;
    int*   sc   = bsum + NB + (NB & 1);   // keep 8B alignment downstream
    unsigned short* WfH = (unsigned short*)(sc + E);       // 24 KB
    unsigned short* WfL = WfH + 12288;                     // 24 KB

    float* out = (float*)d_out;

    (void)hipMemsetAsync(cnt, 0, (size_t)N * sizeof(int), stream);

    // 0) W -> hi/lo MFMA fragment order (48 KB, single block)
    prep_w_kernel<<<1, 256, 0, stream>>>(Wq, Wk, Wv, WfH, WfL);

    // 1) QKV projection (split-precision MFMA, Wf in LDS, paired outputs)
    qkv_kernel<<<(N + 63) / 64, 256, 0, stream>>>(emb, WfH, WfL, N, Q, KVP);

    // 2) Counting sort of edges by destination (4 dispatches)
    histo_kernel<<<(E + 255) / 256, 256, 0, stream>>>(rows, cnt, E);
    block_sum_kernel<<<NB, 256, 0, stream>>>(cnt, bsum, N);
    block_scan_kernel<<<NB, 256, 0, stream>>>(cnt, bsum, off, cur, N, E, NB);
    scatter_kernel<<<(E + 255) / 256, 256, 0, stream>>>(rows, cols, cur, sc, E);

    // 3) Atomic-free aggregation: one wave per node, 2 edges per wave-step
    aggregate_kernel<<<((size_t)N * 64 + 255) / 256, 256, 0, stream>>>(
        off, sc, Q, KVP, out, N);
}